// Round 7
// baseline (88.176 us; speedup 1.0000x reference)
//
#include <hip/hip_runtime.h>

#define BB 8
#define TT 2048
#define DD 128
#define CH 8               // k-chunks (256 rows each): gram grid = CH*BB = 64 blocks
#define GT_STRIDE 72       // bf16 elems per Gt row (64 + 8 pad)
#define DS_STRIDE 136      // bf16 elems per Ds row (128 + 8 pad)

typedef __attribute__((ext_vector_type(8))) short bf16x8;
typedef __attribute__((ext_vector_type(4))) float f32x4;
typedef unsigned short u16;

static __device__ __forceinline__ float bf2f(u16 u) {
    union { unsigned int i; float f; } v; v.i = ((unsigned int)u) << 16; return v.f;
}
static __device__ __forceinline__ u16 f2bf(float f) {
    union { float f; unsigned int i; } v; v.f = f;
    unsigned int x = v.i;
    return (u16)((x + 0x7FFFu + ((x >> 16) & 1u)) >> 16);  // RNE
}

// ===========================================================================
// Kernel 1: MFMA partial Gram. P[chunk][b] = enc_chunk^T @ enc_chunk (K=256,
// processed as 4 sub-tiles of 64 rows through the same 18 KB LDS transpose).
//
// P layout (R6-proven, frag-keyed): within each 16x16 tile, producing lane
// (q,ln) stores its 4 C-regs at elem offset ln*16 + (q>>1)*8 + (q&1)*4, so
// the consumer's B-fragment is one contiguous 16B group. Element-wise
// reduction over chunks preserves the layout.
// ===========================================================================
__global__ __launch_bounds__(256, 1) void gram_mfma(const float* __restrict__ enc,
                                                    u16* __restrict__ P) {
    const int b     = blockIdx.y;
    const int chunk = blockIdx.x;          // 0..7, 256 rows each
    const int t     = threadIdx.x;

    __shared__ __align__(16) u16 Gt[DD * GT_STRIDE];   // [d][k] = enc^T, 18 KB

    const int d  = t & 127;
    const int kh = t >> 7;                 // 0..1
    const int wave = t >> 6, lane = t & 63, quad = lane >> 4, ln = lane & 15;

    f32x4 acc[2][8];
    #pragma unroll
    for (int mi = 0; mi < 2; ++mi)
        #pragma unroll
        for (int nt = 0; nt < 8; ++nt) acc[mi][nt] = (f32x4){0.f, 0.f, 0.f, 0.f};

    for (int tt = 0; tt < 4; ++tt) {
        const float* src = enc + ((size_t)b * TT + (size_t)chunk * 256 + tt * 64) * DD;
        if (tt) __syncthreads();           // protect Gt from previous readers
        #pragma unroll
        for (int a = 0; a < 8; ++a) {
            const int k4 = a * 2 + kh;     // 0..15
            u16 o[4];
            #pragma unroll
            for (int i = 0; i < 4; ++i)
                o[i] = f2bf(src[(k4 * 4 + i) * DD + d]);
            *(ushort4*)&Gt[d * GT_STRIDE + k4 * 4] = *(const ushort4*)o;
        }
        __syncthreads();

        bf16x8 afrag[2][2];
        #pragma unroll
        for (int mi = 0; mi < 2; ++mi)
            #pragma unroll
            for (int ks = 0; ks < 2; ++ks)
                afrag[mi][ks] = *(const bf16x8*)&Gt[((wave * 2 + mi) * 16 + ln) * GT_STRIDE
                                                    + ks * 32 + quad * 8];
        #pragma unroll
        for (int ks = 0; ks < 2; ++ks) {
            #pragma unroll
            for (int nt = 0; nt < 8; ++nt) {
                const bf16x8 bfrag = *(const bf16x8*)&Gt[(nt * 16 + ln) * GT_STRIDE
                                                         + ks * 32 + quad * 8];
                #pragma unroll
                for (int mi = 0; mi < 2; ++mi)
                    acc[mi][nt] = __builtin_amdgcn_mfma_f32_16x16x32_bf16(
                        afrag[mi][ks], bfrag, acc[mi][nt], 0, 0, 0);
            }
        }
    }

    // Epilogue: b64 stores in the frag-keyed layout (512B contiguous per tile).
    u16* Pb = P + ((size_t)chunk * BB + b) * (DD * DD);
    const int off = ln * 16 + (quad >> 1) * 8 + (quad & 1) * 4;
    #pragma unroll
    for (int mi = 0; mi < 2; ++mi) {
        #pragma unroll
        for (int nt = 0; nt < 8; ++nt) {
            u16 o[4];
            #pragma unroll
            for (int r = 0; r < 4; ++r) o[r] = f2bf(acc[mi][nt][r]);
            const int tile = (wave * 2 + mi) * 8 + nt;
            *(ushort4*)&Pb[tile * 256 + off] = *(const ushort4*)o;
        }
    }
}

// ===========================================================================
// Kernel 2: fused reduce + apply. Each block reduces the CH=8 partials of its
// batch directly into LDS Gs (frag-keyed layout passes through element-wise
// reduction), then out[b] = dec[b] @ G[b] via MFMA.
// Grid (32 q-chunks, 8 batches). Dec staging + MFMA loop + epilogue are the
// R5/R6 HW-verified code.
// ===========================================================================
__global__ __launch_bounds__(256, 1) void apply_mfma(const float* __restrict__ dec,
                                                     const u16* __restrict__ P,
                                                     float* __restrict__ out) {
    const int b     = blockIdx.y;
    const int chunk = blockIdx.x;
    const int t     = threadIdx.x;

    __shared__ __align__(16) u16 Gs[DD * DD];          // 32 KB, frag-keyed layout
    __shared__ __align__(16) u16 Ds[64 * DS_STRIDE];   // 17 KB

    // ---- reduce P[0..CH)[b] -> Gs (bf16), coalesced ushort4 groups --------
    {
        const ushort4* Pu = (const ushort4*)P;
        const int cstride = BB * DD * DD / 4;          // ushort4 groups per chunk
        const int bbase   = b * (DD * DD / 4);
        #pragma unroll 4
        for (int i = 0; i < 16; ++i) {
            const int g = i * 256 + t;                 // 0..4095
            float sx = 0.f, sy = 0.f, sz = 0.f, sw = 0.f;
            #pragma unroll
            for (int c = 0; c < CH; ++c) {
                const ushort4 v = Pu[(size_t)c * cstride + bbase + g];
                sx += bf2f(v.x); sy += bf2f(v.y); sz += bf2f(v.z); sw += bf2f(v.w);
            }
            u16 o[4] = {f2bf(sx), f2bf(sy), f2bf(sz), f2bf(sw)};
            *(ushort4*)&Gs[g * 4] = *(const ushort4*)o;
        }
    }

    // ---- stage dec tile (64 x 128) fp32 -> bf16 ---------------------------
    const float4* dsrc = (const float4*)(dec + ((size_t)b * TT + (size_t)chunk * 64) * DD);
    #pragma unroll
    for (int i = 0; i < 8; ++i) {
        const int idx = i * 256 + t;
        const int row = idx >> 5, c4 = idx & 31;
        const float4 v = dsrc[idx];
        u16 o[4] = {f2bf(v.x), f2bf(v.y), f2bf(v.z), f2bf(v.w)};
        *(ushort4*)&Ds[row * DS_STRIDE + c4 * 4] = *(const ushort4*)o;
    }
    __syncthreads();

    const int wave = t >> 6, lane = t & 63, quad = lane >> 4, ln = lane & 15;
    const int qt = wave * 16;

    f32x4 acc[8];
    #pragma unroll
    for (int dt = 0; dt < 8; ++dt) acc[dt] = (f32x4){0.f, 0.f, 0.f, 0.f};

    #pragma unroll
    for (int ks = 0; ks < 4; ++ks) {
        const bf16x8 a = *(const bf16x8*)&Ds[(qt + ln) * DS_STRIDE + ks * 32 + quad * 8];
        const int mtk  = ks * 2 + (quad >> 1);
        const int boff = ln * 16 + (quad & 1) * 8;
        #pragma unroll
        for (int dt = 0; dt < 8; ++dt) {
            const bf16x8 bb = *(const bf16x8*)&Gs[(mtk * 8 + dt) * 256 + boff];
            acc[dt] = __builtin_amdgcn_mfma_f32_16x16x32_bf16(a, bb, acc[dt], 0, 0, 0);
        }
    }

    // Epilogue: C/D layout col=lane&15, row=quad*4+reg (HW-verified R4-R6).
    float* ob = out + ((size_t)b * TT + (size_t)chunk * 64) * DD;
    #pragma unroll
    for (int dt = 0; dt < 8; ++dt) {
        const int dcol = dt * 16 + ln;
        #pragma unroll
        for (int r = 0; r < 4; ++r) {
            const int q = qt + quad * 4 + r;
            ob[q * DD + dcol] = acc[dt][r];
        }
    }
}

extern "C" void kernel_launch(void* const* d_in, const int* in_sizes, int n_in,
                              void* d_out, int out_size, void* d_ws, size_t ws_size,
                              hipStream_t stream) {
    const float* enc = (const float*)d_in[0];  // (8,2048,128) fp32
    const float* dec = (const float*)d_in[1];  // (8,2048,128) fp32
    float* out = (float*)d_out;                // (8,2048,128) fp32

    u16* P = (u16*)d_ws;                       // CH*8*128*128 bf16 = 2 MB

    gram_mfma<<<dim3(CH, BB), 256, 0, stream>>>(enc, P);
    apply_mfma<<<dim3(TT / 64, BB), 256, 0, stream>>>(dec, P, out);
}

// Round 8
// 75.898 us; speedup vs baseline: 1.1618x; 1.1618x over previous
//
#include <hip/hip_runtime.h>

#define BB 8
#define TT 2048
#define DD 128
#define CH 16              // k-chunks (128 rows each): gram grid = CH*BB = 128 blocks
#define GT_STRIDE 72       // bf16 elems per Gt row (64 + 8 pad)
#define DS_STRIDE 136      // bf16 elems per Ds row (128 + 8 pad)

typedef __attribute__((ext_vector_type(8))) short bf16x8;
typedef __attribute__((ext_vector_type(4))) float f32x4;
typedef unsigned short u16;

static __device__ __forceinline__ float bf2f(u16 u) {
    union { unsigned int i; float f; } v; v.i = ((unsigned int)u) << 16; return v.f;
}
static __device__ __forceinline__ u16 f2bf(float f) {
    union { float f; unsigned int i; } v; v.f = f;
    unsigned int x = v.i;
    return (u16)((x + 0x7FFFu + ((x >> 16) & 1u)) >> 16);  // RNE
}

// ===========================================================================
// Kernel 1: MFMA partial Gram. P[chunk][b] = enc_chunk^T @ enc_chunk (K=128,
// two 64-row sub-tiles through the 18 KB LDS transpose; loop proven in R7).
//
// P layout (R6-proven, frag-keyed): within each 16x16 tile, producing lane
// (q,ln) stores its 4 C-regs at elem offset ln*16 + (q>>1)*8 + (q&1)*4, so
// the apply kernel's B-fragment is ONE contiguous 16B group (single
// ds_read_b128). Element-wise reduction over chunks preserves the layout.
// ===========================================================================
__global__ __launch_bounds__(256, 1) void gram_mfma(const float* __restrict__ enc,
                                                    u16* __restrict__ P) {
    const int b     = blockIdx.y;
    const int chunk = blockIdx.x;          // 0..CH-1, 128 rows each
    const int t     = threadIdx.x;

    __shared__ __align__(16) u16 Gt[DD * GT_STRIDE];   // [d][k] = enc^T, 18 KB

    const int d  = t & 127;
    const int kh = t >> 7;                 // 0..1
    const int wave = t >> 6, lane = t & 63, quad = lane >> 4, ln = lane & 15;

    f32x4 acc[2][8];
    #pragma unroll
    for (int mi = 0; mi < 2; ++mi)
        #pragma unroll
        for (int nt = 0; nt < 8; ++nt) acc[mi][nt] = (f32x4){0.f, 0.f, 0.f, 0.f};

    #pragma unroll
    for (int tt = 0; tt < 2; ++tt) {
        const float* src = enc + ((size_t)b * TT + (size_t)chunk * 128 + tt * 64) * DD;
        if (tt) __syncthreads();           // protect Gt from previous readers
        #pragma unroll
        for (int a = 0; a < 8; ++a) {
            const int k4 = a * 2 + kh;     // 0..15
            u16 o[4];
            #pragma unroll
            for (int i = 0; i < 4; ++i)
                o[i] = f2bf(src[(k4 * 4 + i) * DD + d]);
            *(ushort4*)&Gt[d * GT_STRIDE + k4 * 4] = *(const ushort4*)o;
        }
        __syncthreads();

        bf16x8 afrag[2][2];
        #pragma unroll
        for (int mi = 0; mi < 2; ++mi)
            #pragma unroll
            for (int ks = 0; ks < 2; ++ks)
                afrag[mi][ks] = *(const bf16x8*)&Gt[((wave * 2 + mi) * 16 + ln) * GT_STRIDE
                                                    + ks * 32 + quad * 8];
        #pragma unroll
        for (int ks = 0; ks < 2; ++ks) {
            #pragma unroll
            for (int nt = 0; nt < 8; ++nt) {
                const bf16x8 bfrag = *(const bf16x8*)&Gt[(nt * 16 + ln) * GT_STRIDE
                                                         + ks * 32 + quad * 8];
                #pragma unroll
                for (int mi = 0; mi < 2; ++mi)
                    acc[mi][nt] = __builtin_amdgcn_mfma_f32_16x16x32_bf16(
                        afrag[mi][ks], bfrag, acc[mi][nt], 0, 0, 0);
            }
        }
    }

    // Epilogue: b64 stores in the frag-keyed layout (512B contiguous per tile).
    u16* Pb = P + ((size_t)chunk * BB + b) * (DD * DD);
    const int off = ln * 16 + (quad >> 1) * 8 + (quad & 1) * 4;
    #pragma unroll
    for (int mi = 0; mi < 2; ++mi) {
        #pragma unroll
        for (int nt = 0; nt < 8; ++nt) {
            u16 o[4];
            #pragma unroll
            for (int r = 0; r < 4; ++r) o[r] = f2bf(acc[mi][nt][r]);
            const int tile = (wave * 2 + mi) * 8 + nt;
            *(ushort4*)&Pb[tile * 256 + off] = *(const ushort4*)o;
        }
    }
}

// ===========================================================================
// Kernel 2: element-wise reduce over chunks: Gw[b] = sum_c P[c][b]  (bf16 out).
// Layout-agnostic. 128 blocks x 256 threads, one ushort4 group each.
// ===========================================================================
__global__ __launch_bounds__(256) void gram_reduce(const u16* __restrict__ P,
                                                   u16* __restrict__ Gw) {
    const int g = blockIdx.x * 256 + threadIdx.x;   // 0..32767
    const ushort4* Pu = (const ushort4*)P;
    const int stride = BB * DD * DD / 4;
    float sx = 0.f, sy = 0.f, sz = 0.f, sw = 0.f;
    #pragma unroll
    for (int c = 0; c < CH; ++c) {
        const ushort4 v = Pu[(size_t)c * stride + g];
        sx += bf2f(v.x); sy += bf2f(v.y); sz += bf2f(v.z); sw += bf2f(v.w);
    }
    ushort4 o; o.x = f2bf(sx); o.y = f2bf(sy); o.z = f2bf(sz); o.w = f2bf(sw);
    ((ushort4*)Gw)[g] = o;
}

// ===========================================================================
// Kernel 3: out[b] = dec[b] @ G[b] via MFMA. Grid (32 q-chunks, 8 batches).
// Gs staged raw (frag-keyed layout); B-frag (mtk,dt,quad,ln) = ONE b128 at
//   tile = (ks*2 + (quad>>1))*8 + dt, elem tile*256 + ln*16 + (quad&1)*8.
// HW-verified R5/R6.
// ===========================================================================
__global__ __launch_bounds__(256, 1) void apply_mfma(const float* __restrict__ dec,
                                                     const u16* __restrict__ Gw,
                                                     float* __restrict__ out) {
    const int b     = blockIdx.y;
    const int chunk = blockIdx.x;
    const int t     = threadIdx.x;

    __shared__ __align__(16) u16 Gs[DD * DD];          // 32 KB, frag-keyed layout
    __shared__ __align__(16) u16 Ds[64 * DS_STRIDE];   // 17 KB

    const uint4* gsrc = (const uint4*)(Gw + (size_t)b * DD * DD);
    #pragma unroll
    for (int i = 0; i < 8; ++i)
        ((uint4*)Gs)[i * 256 + t] = gsrc[i * 256 + t];

    const float4* dsrc = (const float4*)(dec + ((size_t)b * TT + (size_t)chunk * 64) * DD);
    #pragma unroll
    for (int i = 0; i < 8; ++i) {
        const int idx = i * 256 + t;
        const int row = idx >> 5, c4 = idx & 31;
        const float4 v = dsrc[idx];
        u16 o[4] = {f2bf(v.x), f2bf(v.y), f2bf(v.z), f2bf(v.w)};
        *(ushort4*)&Ds[row * DS_STRIDE + c4 * 4] = *(const ushort4*)o;
    }
    __syncthreads();

    const int wave = t >> 6, lane = t & 63, quad = lane >> 4, ln = lane & 15;
    const int qt = wave * 16;

    f32x4 acc[8];
    #pragma unroll
    for (int dt = 0; dt < 8; ++dt) acc[dt] = (f32x4){0.f, 0.f, 0.f, 0.f};

    #pragma unroll
    for (int ks = 0; ks < 4; ++ks) {
        const bf16x8 a = *(const bf16x8*)&Ds[(qt + ln) * DS_STRIDE + ks * 32 + quad * 8];
        const int mtk  = ks * 2 + (quad >> 1);
        const int boff = ln * 16 + (quad & 1) * 8;
        #pragma unroll
        for (int dt = 0; dt < 8; ++dt) {
            const bf16x8 bb = *(const bf16x8*)&Gs[(mtk * 8 + dt) * 256 + boff];
            acc[dt] = __builtin_amdgcn_mfma_f32_16x16x32_bf16(a, bb, acc[dt], 0, 0, 0);
        }
    }

    // Epilogue: C/D layout col=lane&15, row=quad*4+reg (HW-verified R4-R6).
    float* ob = out + ((size_t)b * TT + (size_t)chunk * 64) * DD;
    #pragma unroll
    for (int dt = 0; dt < 8; ++dt) {
        const int dcol = dt * 16 + ln;
        #pragma unroll
        for (int r = 0; r < 4; ++r) {
            const int q = qt + quad * 4 + r;
            ob[q * DD + dcol] = acc[dt][r];
        }
    }
}

extern "C" void kernel_launch(void* const* d_in, const int* in_sizes, int n_in,
                              void* d_out, int out_size, void* d_ws, size_t ws_size,
                              hipStream_t stream) {
    const float* enc = (const float*)d_in[0];  // (8,2048,128) fp32
    const float* dec = (const float*)d_in[1];  // (8,2048,128) fp32
    float* out = (float*)d_out;                // (8,2048,128) fp32

    // ws: P bf16 partials (CH * 256 KB = 4 MB) | Gw bf16 (256 KB)
    u16* P  = (u16*)d_ws;
    u16* Gw = (u16*)((char*)d_ws + (size_t)CH * BB * DD * DD * sizeof(u16));

    gram_mfma<<<dim3(CH, BB), 256, 0, stream>>>(enc, P);
    gram_reduce<<<BB * DD * DD / 4 / 256, 256, 0, stream>>>(P, Gw);
    apply_mfma<<<dim3(TT / 64, BB), 256, 0, stream>>>(dec, Gw, out);
}

// Round 9
// 75.622 us; speedup vs baseline: 1.1660x; 1.0037x over previous
//
#include <hip/hip_runtime.h>

#define BB 8
#define TT 2048
#define DD 128
#define CH 16              // k-chunks (128 rows each): gram grid = CH*BB = 128 blocks
#define GT_STRIDE 72       // bf16 elems per Gt row (64 + 8 pad)

typedef __attribute__((ext_vector_type(8))) short bf16x8;
typedef __attribute__((ext_vector_type(4))) float f32x4;
typedef unsigned short u16;

static __device__ __forceinline__ float bf2f(u16 u) {
    union { unsigned int i; float f; } v; v.i = ((unsigned int)u) << 16; return v.f;
}
static __device__ __forceinline__ u16 f2bf(float f) {
    union { float f; unsigned int i; } v; v.f = f;
    unsigned int x = v.i;
    return (u16)((x + 0x7FFFu + ((x >> 16) & 1u)) >> 16);  // RNE
}

// ===========================================================================
// Kernel 1: MFMA partial Gram. P[chunk][b] = enc_chunk^T @ enc_chunk (K=128,
// two 64-row sub-tiles through the 18 KB LDS transpose). Byte-identical to R8.
//
// P layout (frag-keyed): within each 16x16 tile, producing lane (q,ln) stores
// its 4 C-regs at elem offset ln*16 + (q>>1)*8 + (q&1)*4, so the apply
// kernel's B-fragment is ONE contiguous 16B group (single ds_read_b128).
// Element-wise reduction over chunks preserves the layout.
// ===========================================================================
__global__ __launch_bounds__(256, 1) void gram_mfma(const float* __restrict__ enc,
                                                    u16* __restrict__ P) {
    const int b     = blockIdx.y;
    const int chunk = blockIdx.x;          // 0..CH-1, 128 rows each
    const int t     = threadIdx.x;

    __shared__ __align__(16) u16 Gt[DD * GT_STRIDE];   // [d][k] = enc^T, 18 KB

    const int d  = t & 127;
    const int kh = t >> 7;                 // 0..1
    const int wave = t >> 6, lane = t & 63, quad = lane >> 4, ln = lane & 15;

    f32x4 acc[2][8];
    #pragma unroll
    for (int mi = 0; mi < 2; ++mi)
        #pragma unroll
        for (int nt = 0; nt < 8; ++nt) acc[mi][nt] = (f32x4){0.f, 0.f, 0.f, 0.f};

    #pragma unroll
    for (int tt = 0; tt < 2; ++tt) {
        const float* src = enc + ((size_t)b * TT + (size_t)chunk * 128 + tt * 64) * DD;
        if (tt) __syncthreads();           // protect Gt from previous readers
        #pragma unroll
        for (int a = 0; a < 8; ++a) {
            const int k4 = a * 2 + kh;     // 0..15
            u16 o[4];
            #pragma unroll
            for (int i = 0; i < 4; ++i)
                o[i] = f2bf(src[(k4 * 4 + i) * DD + d]);
            *(ushort4*)&Gt[d * GT_STRIDE + k4 * 4] = *(const ushort4*)o;
        }
        __syncthreads();

        bf16x8 afrag[2][2];
        #pragma unroll
        for (int mi = 0; mi < 2; ++mi)
            #pragma unroll
            for (int ks = 0; ks < 2; ++ks)
                afrag[mi][ks] = *(const bf16x8*)&Gt[((wave * 2 + mi) * 16 + ln) * GT_STRIDE
                                                    + ks * 32 + quad * 8];
        #pragma unroll
        for (int ks = 0; ks < 2; ++ks) {
            #pragma unroll
            for (int nt = 0; nt < 8; ++nt) {
                const bf16x8 bfrag = *(const bf16x8*)&Gt[(nt * 16 + ln) * GT_STRIDE
                                                         + ks * 32 + quad * 8];
                #pragma unroll
                for (int mi = 0; mi < 2; ++mi)
                    acc[mi][nt] = __builtin_amdgcn_mfma_f32_16x16x32_bf16(
                        afrag[mi][ks], bfrag, acc[mi][nt], 0, 0, 0);
            }
        }
    }

    // Epilogue: b64 stores in the frag-keyed layout (512B contiguous per tile).
    u16* Pb = P + ((size_t)chunk * BB + b) * (DD * DD);
    const int off = ln * 16 + (quad >> 1) * 8 + (quad & 1) * 4;
    #pragma unroll
    for (int mi = 0; mi < 2; ++mi) {
        #pragma unroll
        for (int nt = 0; nt < 8; ++nt) {
            u16 o[4];
            #pragma unroll
            for (int r = 0; r < 4; ++r) o[r] = f2bf(acc[mi][nt][r]);
            const int tile = (wave * 2 + mi) * 8 + nt;
            *(ushort4*)&Pb[tile * 256 + off] = *(const ushort4*)o;
        }
    }
}

// ===========================================================================
// Kernel 2: element-wise reduce over chunks: Gw[b] = sum_c P[c][b]  (bf16 out).
// Layout-agnostic. 128 blocks x 256 threads. Byte-identical to R8.
// ===========================================================================
__global__ __launch_bounds__(256) void gram_reduce(const u16* __restrict__ P,
                                                   u16* __restrict__ Gw) {
    const int g = blockIdx.x * 256 + threadIdx.x;   // 0..32767
    const ushort4* Pu = (const ushort4*)P;
    const int stride = BB * DD * DD / 4;
    float sx = 0.f, sy = 0.f, sz = 0.f, sw = 0.f;
    #pragma unroll
    for (int c = 0; c < CH; ++c) {
        const ushort4 v = Pu[(size_t)c * stride + g];
        sx += bf2f(v.x); sy += bf2f(v.y); sz += bf2f(v.z); sw += bf2f(v.w);
    }
    ushort4 o; o.x = f2bf(sx); o.y = f2bf(sy); o.z = f2bf(sz); o.w = f2bf(sw);
    ((ushort4*)Gw)[g] = o;
}

// ===========================================================================
// Kernel 3: out[b] = dec[b] @ G[b] via MFMA. Grid (32 q-chunks, 8 batches).
// NEW in R9: A-fragments (dec) loaded DIRECTLY from global (8 consecutive
// fp32 per lane per kstep = 128B contiguous per row across a wave), converted
// fp32->bf16 in registers BEFORE the Gs barrier. No Ds LDS at all.
// Gs staging + B-frag read + epilogue identical to R8 (HW-verified).
// ===========================================================================
__global__ __launch_bounds__(256, 1) void apply_mfma(const float* __restrict__ dec,
                                                     const u16* __restrict__ Gw,
                                                     float* __restrict__ out) {
    const int b     = blockIdx.y;
    const int chunk = blockIdx.x;
    const int t     = threadIdx.x;

    __shared__ __align__(16) u16 Gs[DD * DD];          // 32 KB, frag-keyed layout

    const int wave = t >> 6, lane = t & 63, quad = lane >> 4, ln = lane & 15;
    const int qt = wave * 16;

    // Issue dec loads first (independent of LDS) so they overlap Gs staging.
    const float* drow = dec + ((size_t)b * TT + (size_t)chunk * 64 + qt + ln) * DD
                        + quad * 8;
    float4 dv[4][2];
    #pragma unroll
    for (int ks = 0; ks < 4; ++ks) {
        dv[ks][0] = *(const float4*)(drow + ks * 32);
        dv[ks][1] = *(const float4*)(drow + ks * 32 + 4);
    }

    // Stage G[b] raw (frag-keyed layout), coalesced uint4.
    const uint4* gsrc = (const uint4*)(Gw + (size_t)b * DD * DD);
    #pragma unroll
    for (int i = 0; i < 8; ++i)
        ((uint4*)Gs)[i * 256 + t] = gsrc[i * 256 + t];

    // Convert A-frags in registers (RNE, identical to R8's staged values).
    bf16x8 afrag[4];
    #pragma unroll
    for (int ks = 0; ks < 4; ++ks) {
        union { u16 o[8]; bf16x8 v; } u;
        u.o[0] = f2bf(dv[ks][0].x); u.o[1] = f2bf(dv[ks][0].y);
        u.o[2] = f2bf(dv[ks][0].z); u.o[3] = f2bf(dv[ks][0].w);
        u.o[4] = f2bf(dv[ks][1].x); u.o[5] = f2bf(dv[ks][1].y);
        u.o[6] = f2bf(dv[ks][1].z); u.o[7] = f2bf(dv[ks][1].w);
        afrag[ks] = u.v;
    }
    __syncthreads();

    f32x4 acc[8];
    #pragma unroll
    for (int dt = 0; dt < 8; ++dt) acc[dt] = (f32x4){0.f, 0.f, 0.f, 0.f};

    #pragma unroll
    for (int ks = 0; ks < 4; ++ks) {
        const int mtk  = ks * 2 + (quad >> 1);
        const int boff = ln * 16 + (quad & 1) * 8;
        #pragma unroll
        for (int dt = 0; dt < 8; ++dt) {
            const bf16x8 bb = *(const bf16x8*)&Gs[(mtk * 8 + dt) * 256 + boff];
            acc[dt] = __builtin_amdgcn_mfma_f32_16x16x32_bf16(afrag[ks], bb, acc[dt], 0, 0, 0);
        }
    }

    // Epilogue: C/D layout col=lane&15, row=quad*4+reg (HW-verified R4-R8).
    float* ob = out + ((size_t)b * TT + (size_t)chunk * 64) * DD;
    #pragma unroll
    for (int dt = 0; dt < 8; ++dt) {
        const int dcol = dt * 16 + ln;
        #pragma unroll
        for (int r = 0; r < 4; ++r) {
            const int q = qt + quad * 4 + r;
            ob[q * DD + dcol] = acc[dt][r];
        }
    }
}

extern "C" void kernel_launch(void* const* d_in, const int* in_sizes, int n_in,
                              void* d_out, int out_size, void* d_ws, size_t ws_size,
                              hipStream_t stream) {
    const float* enc = (const float*)d_in[0];  // (8,2048,128) fp32
    const float* dec = (const float*)d_in[1];  // (8,2048,128) fp32
    float* out = (float*)d_out;                // (8,2048,128) fp32

    // ws: P bf16 partials (CH * 256 KB = 4 MB) | Gw bf16 (256 KB)
    u16* P  = (u16*)d_ws;
    u16* Gw = (u16*)((char*)d_ws + (size_t)CH * BB * DD * DD * sizeof(u16));

    gram_mfma<<<dim3(CH, BB), 256, 0, stream>>>(enc, P);
    gram_reduce<<<BB * DD * DD / 4 / 256, 256, 0, stream>>>(P, Gw);
    apply_mfma<<<dim3(TT / 64, BB), 256, 0, stream>>>(dec, Gw, out);
}